// Round 5
// baseline (244.203 us; speedup 1.0000x reference)
//
#include <hip/hip_runtime.h>
#include <hip/hip_bf16.h>
#include <cstdint>

// GatedMultiheadAttention: B=2, N=2048, E=1024, H=16, D=64
// R5: split-K attention (mergeable no-max exp2 softmax): 2048 blocks, BK=32,
// LDS 20KB -> 8 blocks/CU = 16 waves/CU (R2/R4 were grid-capped at 8 waves/CU).
// Partial O bf16 + l fp32, merged by a small kernel. gemm_qkv forced to
// VGPR<=170 via __launch_bounds__(256,3) so 3 blocks/CU can be resident.
// ws (48MB): lp@0 (over dead WQ region start.. weights 0-8, WOB@6-8 stays),
// XQ 8-16 (->AOB), XK 16-24 (->Opart ks0), XV 24-32 (->Opart ks1),
// QB 32-40, KB 40-48. VTB = d_out (dead until final GEMM).

#define DEV __device__ __forceinline__
typedef __attribute__((ext_vector_type(8))) short bf16x8;
typedef __attribute__((ext_vector_type(4))) float f32x4;
typedef unsigned short u16;

DEV void async16(const void* g, void* l) {
  __builtin_amdgcn_global_load_lds(
      (const __attribute__((address_space(1))) unsigned int*)g,
      (__attribute__((address_space(3))) unsigned int*)l, 16, 0, 0);
}

DEV u16 bf16_rne(float f) {
  unsigned int u = __builtin_bit_cast(unsigned int, f);
  u += 0x7FFFu + ((u >> 16) & 1u);
  return (u16)(u >> 16);
}

DEV u16 cvt16(float x) {
  __hip_bfloat16 h = __float2bfloat16(x);
  return __builtin_bit_cast(u16, h);
}

// ---------------- one fused cast: q,k,v + 4 weights ----------------
__global__ __launch_bounds__(256) void cast_all(
    const float* __restrict__ q, const float* __restrict__ k, const float* __restrict__ v,
    const float* __restrict__ Wq, const float* __restrict__ Wk,
    const float* __restrict__ Wv, const float* __restrict__ Wo,
    u16* __restrict__ XQ, u16* __restrict__ XK, u16* __restrict__ XV,
    u16* __restrict__ WQB, u16* __restrict__ WKB, u16* __restrict__ WVB,
    u16* __restrict__ WOB) {
  int idx = blockIdx.x * 256 + threadIdx.x;  // one 8-elem item each
  const float* src; u16* dst; int i;
  if      (idx <  524288) { src = q;  dst = XQ;  i = idx; }
  else if (idx < 1048576) { src = k;  dst = XK;  i = idx -  524288; }
  else if (idx < 1572864) { src = v;  dst = XV;  i = idx - 1048576; }
  else if (idx < 1703936) { src = Wq; dst = WQB; i = idx - 1572864; }
  else if (idx < 1835008) { src = Wk; dst = WKB; i = idx - 1703936; }
  else if (idx < 1966080) { src = Wv; dst = WVB; i = idx - 1835008; }
  else                    { src = Wo; dst = WOB; i = idx - 1966080; }
  const float4* p = (const float4*)src + (size_t)i * 2;
  float4 a = p[0], b = p[1];
  union { u16 us[8]; uint4 vv; } u;
  u.us[0] = bf16_rne(a.x); u.us[1] = bf16_rne(a.y);
  u.us[2] = bf16_rne(a.z); u.us[3] = bf16_rne(a.w);
  u.us[4] = bf16_rne(b.x); u.us[5] = bf16_rne(b.y);
  u.us[6] = bf16_rne(b.z); u.us[7] = bf16_rne(b.w);
  ((uint4*)dst)[i] = u.vv;
}

// ---------------- fused QKV projection GEMM (768 blocks, 128x128, dbuf) ------
// seg = bx>>8: 0=Q (gate-scale folded), 1=K, 2=V (writes V^T into d_out).
// launch_bounds (256,3): cap VGPR at 170 so the 3-blocks/CU grid is resident.
__global__ __launch_bounds__(256, 3) void gemm_qkv(
    const u16* __restrict__ XQ, const u16* __restrict__ XK, const u16* __restrict__ XV,
    const u16* __restrict__ Wb,  // WQ|WK|WV contiguous, 1M elems apart
    const float* __restrict__ bq, const float* __restrict__ bkb, const float* __restrict__ bv,
    const float* __restrict__ gate,
    u16* __restrict__ QB, u16* __restrict__ KB, u16* __restrict__ VTB) {
  __shared__ __attribute__((aligned(16))) u16 As[2][128 * 32];
  __shared__ __attribute__((aligned(16))) u16 Bs[2][128 * 32];
  const int t = threadIdx.x, lane = t & 63, w = t >> 6;
  const int l15 = lane & 15, quad = lane >> 4;
  const int seg = blockIdx.x >> 8, inner = blockIdx.x & 255;
  const int bm = inner >> 3, bn = inner & 7;
  const int m0 = bm << 7, n0 = bn << 7;
  const u16* A = (seg == 0) ? XQ : (seg == 1) ? XK : XV;
  const u16* W = Wb + (long)seg * 1048576;
  const int wm = (w >> 1) << 6, wn = (w & 1) << 6;
  const int r0 = t >> 2, cc0 = (t & 3) * 8;
  const u16* gA0 = A + (long)(m0 + r0) * 1024 + cc0;
  const u16* gA1 = gA0 + 64 * 1024;
  const u16* gB0 = W + (long)(n0 + r0) * 1024 + cc0;
  const u16* gB1 = gB0 + 64 * 1024;

  async16(gA0, &As[0][t * 8]); async16(gA1, &As[0][(t + 256) * 8]);
  async16(gB0, &Bs[0][t * 8]); async16(gB1, &Bs[0][(t + 256) * 8]);

  f32x4 acc[4][4] = {};
  for (int k0 = 0; k0 < 1024; k0 += 32) {
    const int cur = (k0 >> 5) & 1;
    __syncthreads();
    if (k0 + 32 < 1024) {
      const int kn = k0 + 32, nb = cur ^ 1;
      async16(gA0 + kn, &As[nb][t * 8]); async16(gA1 + kn, &As[nb][(t + 256) * 8]);
      async16(gB0 + kn, &Bs[nb][t * 8]); async16(gB1 + kn, &Bs[nb][(t + 256) * 8]);
    }
    bf16x8 af[4], bfm[4];
#pragma unroll
    for (int i = 0; i < 4; i++)
      af[i] = *(const bf16x8*)&As[cur][(wm + i * 16 + l15) * 32 + quad * 8];
#pragma unroll
    for (int j = 0; j < 4; j++)
      bfm[j] = *(const bf16x8*)&Bs[cur][(wn + j * 16 + l15) * 32 + quad * 8];
#pragma unroll
    for (int i = 0; i < 4; i++)
#pragma unroll
      for (int j = 0; j < 4; j++)
        acc[i][j] = __builtin_amdgcn_mfma_f32_16x16x32_bf16(af[i], bfm[j], acc[i][j], 0, 0, 0);
  }

  if (seg == 2) {  // V: bias + transposed write V^T[(b*1024+col)*2048 + n]
#pragma unroll
    for (int i = 0; i < 4; i++) {
      int token = m0 + wm + i * 16 + quad * 4;
      int bb_ = token >> 11, n = token & 2047;
#pragma unroll
      for (int j = 0; j < 4; j++) {
        int col = n0 + wn + j * 16 + l15;
        float bb = bv[col];
        union { u16 us[4]; uint2 u2; } pk;
#pragma unroll
        for (int r = 0; r < 4; r++) pk.us[r] = bf16_rne(acc[i][j][r] + bb);
        *(uint2*)&VTB[(long)(bb_ * 1024 + col) * 2048 + n] = pk.u2;
      }
    }
  } else {
    const float* bias = seg ? bkb : bq;
    u16* C = seg ? KB : QB;
#pragma unroll
    for (int j = 0; j < 4; j++) {
      int col = n0 + wn + j * 16 + l15;
      float bb = bias[col];
      float scl = 1.f;
      if (seg == 0) {
        float g = gate[col >> 6];
        float sig = 1.f / (1.f + __builtin_amdgcn_exp2f(-g * 1.44269504f));
        scl = sig * 0.125f * 1.44269504f;
      }
#pragma unroll
      for (int i = 0; i < 4; i++) {
        int row = m0 + wm + i * 16 + quad * 4;
#pragma unroll
        for (int r = 0; r < 4; r++)
          C[(long)(row + r) * 1024 + col] = bf16_rne((acc[i][j][r] + bb) * scl);
      }
    }
  }
}

// ---------------- out-proj GEMM: 64x128 tiles, dbuf, fp32 out ----------------
__global__ __launch_bounds__(256, 2) void gemm_out(
    const u16* __restrict__ A, const u16* __restrict__ W,
    const float* __restrict__ bias, float* __restrict__ Cf) {
  __shared__ __attribute__((aligned(16))) u16 As[2][64 * 32];
  __shared__ __attribute__((aligned(16))) u16 Bs[2][128 * 32];
  const int t = threadIdx.x, lane = t & 63, w = t >> 6;
  const int l15 = lane & 15, quad = lane >> 4;
  const int bm = blockIdx.x >> 3, bn = blockIdx.x & 7;
  const int m0 = bm << 6, n0 = bn << 7;
  const int wm = (w >> 1) << 5, wn = (w & 1) << 6;
  const int r0 = t >> 2, cc0 = (t & 3) * 8;
  const u16* gA = A + (long)(m0 + r0) * 1024 + cc0;
  const u16* gB0 = W + (long)(n0 + r0) * 1024 + cc0;
  const u16* gB1 = gB0 + 64 * 1024;

  async16(gA, &As[0][t * 8]);
  async16(gB0, &Bs[0][t * 8]); async16(gB1, &Bs[0][(t + 256) * 8]);

  f32x4 acc[2][4] = {};
  for (int k0 = 0; k0 < 1024; k0 += 32) {
    const int cur = (k0 >> 5) & 1;
    __syncthreads();
    if (k0 + 32 < 1024) {
      const int kn = k0 + 32, nb = cur ^ 1;
      async16(gA + kn, &As[nb][t * 8]);
      async16(gB0 + kn, &Bs[nb][t * 8]); async16(gB1 + kn, &Bs[nb][(t + 256) * 8]);
    }
    bf16x8 af[2], bfm[4];
#pragma unroll
    for (int i = 0; i < 2; i++)
      af[i] = *(const bf16x8*)&As[cur][(wm + i * 16 + l15) * 32 + quad * 8];
#pragma unroll
    for (int j = 0; j < 4; j++)
      bfm[j] = *(const bf16x8*)&Bs[cur][(wn + j * 16 + l15) * 32 + quad * 8];
#pragma unroll
    for (int i = 0; i < 2; i++)
#pragma unroll
      for (int j = 0; j < 4; j++)
        acc[i][j] = __builtin_amdgcn_mfma_f32_16x16x32_bf16(af[i], bfm[j], acc[i][j], 0, 0, 0);
  }

#pragma unroll
  for (int j = 0; j < 4; j++) {
    int col = n0 + wn + j * 16 + l15;
    float bb = bias[col];
#pragma unroll
    for (int i = 0; i < 2; i++) {
      int row = m0 + wm + i * 16 + quad * 4;
#pragma unroll
      for (int r = 0; r < 4; r++)
        Cf[(long)(row + r) * 1024 + col] = acc[i][j][r] + bb;
    }
  }
}

// ---------------- split-K flash attention ----------------
// grid (64,16,2) x 128 thr: bx = qt*2 + ksplit; 2 waves x 32 q-rows, BK=32,
// each block covers 1024 keys (32 ktiles). LDS 20KB -> 8 blocks/CU = 16 waves.
// No-max exp2 softmax (Q pre-scaled) => partials merge by simple addition.
// Outputs: Op[ksplit][tok*1024+h*64+d] bf16 (unnormalized), lp[ksplit][tok*16+h] f32.
__global__ __launch_bounds__(128, 4) void attn_kernel(
    const u16* __restrict__ Q, const u16* __restrict__ Kb,
    const u16* __restrict__ Vt, u16* __restrict__ Op, float* __restrict__ lp) {
  __shared__ __attribute__((aligned(16))) u16 Ks[2][32 * 64];  // [key][d], 128B rows
  __shared__ __attribute__((aligned(16))) u16 Vs[2][64 * 32];  // [d][key], 64B rows
  __shared__ __attribute__((aligned(16))) u16 Ps[2][32 * 32];  // per-wave [q][key], 64B rows
  const int t = threadIdx.x, lane = t & 63, w = t >> 6;
  const int l15 = lane & 15, quad = lane >> 4;
  const int qt = blockIdx.x >> 1, ksp = blockIdx.x & 1;
  const int h = blockIdx.y, b = blockIdx.z;
  const int q0 = qt * 64, tok0 = b * 2048, key0 = ksp * 1024;
  const u16* Kbase = Kb + (long)tok0 * 1024 + h * 64;
  const u16* Vbase = Vt + (long)(b * 1024 + h * 64) * 2048;

  // loop-invariant Q fragments (wave rows q0 + w*32 .. +31)
  bf16x8 aq[2][2];
#pragma unroll
  for (int i = 0; i < 2; i++) {
    long row = tok0 + q0 + w * 32 + i * 16 + l15;
#pragma unroll
    for (int ks = 0; ks < 2; ks++)
      aq[i][ks] = *(const bf16x8*)&Q[row * 1024 + h * 64 + ks * 32 + quad * 8];
  }

  // stage kt=0. K swizzle: chunk^(row&7) (8 chunks/row); V: chunk^((row>>2)&3).
#pragma unroll
  for (int i = 0; i < 2; i++) {
    int c = i * 128 + t;
    int rk = c >> 3, ck = c & 7, cks = ck ^ (rk & 7);
    async16(&Kbase[(long)(key0 + rk) * 1024 + cks * 8], &Ks[0][c * 8]);
    int rv = c >> 2, cv = c & 3, cvs = cv ^ ((rv >> 2) & 3);
    async16(&Vbase[(long)rv * 2048 + key0 + cvs * 8], &Vs[0][c * 8]);
  }

  float l_st[2][4] = {};
  f32x4 O[2][4] = {};

  for (int kt = 0; kt < 32; kt++) {
    const int cur = kt & 1;
    __syncthreads();
    if (kt + 1 < 32) {
      const int k0n = key0 + (kt + 1) * 32, nb = cur ^ 1;
#pragma unroll
      for (int i = 0; i < 2; i++) {
        int c = i * 128 + t;
        int rk = c >> 3, ck = c & 7, cks = ck ^ (rk & 7);
        async16(&Kbase[(long)(k0n + rk) * 1024 + cks * 8], &Ks[nb][c * 8]);
        int rv = c >> 2, cv = c & 3, cvs = cv ^ ((rv >> 2) & 3);
        async16(&Vbase[(long)rv * 2048 + k0n + cvs * 8], &Vs[nb][c * 8]);
      }
    }

    // S = Q K^T (exp2 domain): 2 q-mtiles x 2 key-ntiles
    f32x4 s[2][2] = {};
#pragma unroll
    for (int ks = 0; ks < 2; ks++) {
      bf16x8 bk_[2];
#pragma unroll
      for (int j = 0; j < 2; j++) {
        int rl = j * 16 + l15;
        bk_[j] = *(const bf16x8*)&Ks[cur][rl * 64 + ((ks * 4 + quad) ^ (rl & 7)) * 8];
      }
#pragma unroll
      for (int i = 0; i < 2; i++)
#pragma unroll
        for (int j = 0; j < 2; j++)
          s[i][j] = __builtin_amdgcn_mfma_f32_16x16x32_bf16(aq[i][ks], bk_[j], s[i][j], 0, 0, 0);
    }

    // exp2 + deferred l + P -> per-wave LDS ([q][key], chunk^((row>>2)&3))
#pragma unroll
    for (int i = 0; i < 2; i++) {
#pragma unroll
      for (int r = 0; r < 4; r++) {
        float p0 = __builtin_amdgcn_exp2f(s[i][0][r]);
        float p1 = __builtin_amdgcn_exp2f(s[i][1][r]);
        l_st[i][r] += p0 + p1;
        const int prow = i * 16 + quad * 4 + r, sw = (prow >> 2) & 3;
        u16* pr = &Ps[w][prow * 32];
        const int hi = l15 >> 3, e0 = l15 & 7;
        pr[((0 + hi) ^ sw) * 8 + e0] = cvt16(p0);
        pr[((2 + hi) ^ sw) * 8 + e0] = cvt16(p1);
      }
    }

    // O += P @ V (single K=32 MFMA pass)
    {
      bf16x8 ap[2], bv_[4];
#pragma unroll
      for (int i = 0; i < 2; i++) {
        int rl = i * 16 + l15;
        ap[i] = *(const bf16x8*)&Ps[w][rl * 32 + ((quad ^ ((rl >> 2) & 3))) * 8];
      }
#pragma unroll
      for (int dj = 0; dj < 4; dj++) {
        int rl = dj * 16 + l15;
        bv_[dj] = *(const bf16x8*)&Vs[cur][rl * 32 + ((quad ^ ((rl >> 2) & 3))) * 8];
      }
#pragma unroll
      for (int i = 0; i < 2; i++)
#pragma unroll
        for (int dj = 0; dj < 4; dj++)
          O[i][dj] = __builtin_amdgcn_mfma_f32_16x16x32_bf16(ap[i], bv_[dj], O[i][dj], 0, 0, 0);
    }
  }

  // epilogue: per-row l reduced over 16 lanes; store raw O (bf16) + l (f32)
#pragma unroll
  for (int i = 0; i < 2; i++) {
#pragma unroll
    for (int r = 0; r < 4; r++) {
      float ls = l_st[i][r];
      ls += __shfl_xor(ls, 1); ls += __shfl_xor(ls, 2);
      ls += __shfl_xor(ls, 4); ls += __shfl_xor(ls, 8);
      long row = tok0 + q0 + w * 32 + i * 16 + quad * 4 + r;
#pragma unroll
      for (int dj = 0; dj < 4; dj++)
        Op[(long)ksp * 4194304 + row * 1024 + h * 64 + dj * 16 + l15] = cvt16(O[i][dj][r]);
      if (l15 == 0) lp[ksp * 65536 + (int)row * 16 + h] = ls;
    }
  }
}

// ---------------- merge split-K partials: AO = (O0+O1)/(l0+l1) ----------------
__global__ __launch_bounds__(256) void merge_kernel(
    const u16* __restrict__ Op, const float* __restrict__ lp,
    u16* __restrict__ AO) {
  int idx = blockIdx.x * 256 + threadIdx.x;  // 524288 chunks of 8 elems
  int tok = idx >> 7, rem = idx & 127, h = rem >> 3;
  float inv = 1.f / (lp[tok * 16 + h] + lp[65536 + tok * 16 + h]);
  union { uint4 v; u16 us[8]; } ua, ub, uo;
  ua.v = ((const uint4*)Op)[idx];
  ub.v = ((const uint4*)Op)[idx + 524288];
#pragma unroll
  for (int j = 0; j < 8; j++) {
    float fa = __builtin_bit_cast(float, (unsigned)((unsigned)ua.us[j] << 16));
    float fb = __builtin_bit_cast(float, (unsigned)((unsigned)ub.us[j] << 16));
    uo.us[j] = cvt16((fa + fb) * inv);
  }
  ((uint4*)AO)[idx] = uo.v;
}

extern "C" void kernel_launch(void* const* d_in, const int* in_sizes, int n_in,
                              void* d_out, int out_size, void* d_ws, size_t ws_size,
                              hipStream_t stream) {
  const float* q  = (const float*)d_in[0];
  const float* k  = (const float*)d_in[1];
  const float* v  = (const float*)d_in[2];
  const float* Wq = (const float*)d_in[3];
  const float* bq = (const float*)d_in[4];
  const float* Wk = (const float*)d_in[5];
  const float* bk = (const float*)d_in[6];
  const float* Wv = (const float*)d_in[7];
  const float* bv = (const float*)d_in[8];
  const float* Wo = (const float*)d_in[9];
  const float* bo = (const float*)d_in[10];
  const float* gate = (const float*)d_in[11];
  float* out = (float*)d_out;
  char* ws = (char*)d_ws;

  const size_t MB = 1u << 20;
  u16* WQB = (u16*)(ws + 0 * MB);   // WQ|WK|WV|WO contiguous (2MB each)
  u16* WKB = (u16*)(ws + 2 * MB);
  u16* WVB = (u16*)(ws + 4 * MB);
  u16* WOB = (u16*)(ws + 6 * MB);
  u16* XQ  = (u16*)(ws + 8 * MB);
  u16* XK  = (u16*)(ws + 16 * MB);
  u16* XV  = (u16*)(ws + 24 * MB);
  u16* QB  = (u16*)(ws + 32 * MB);
  u16* KB  = (u16*)(ws + 40 * MB);
  u16* AOB = (u16*)(ws + 8 * MB);     // over dead XQ
  u16* OPp = (u16*)(ws + 16 * MB);    // 16MB partial O (over dead XK/XV)
  float* LP = (float*)(ws + 0 * MB);  // 512KB partial l (over dead WQB)
  u16* VTB = (u16*)d_out;             // d_out as scratch until final GEMM

  cast_all<<<8192, 256, 0, stream>>>(q, k, v, Wq, Wk, Wv, Wo,
                                     XQ, XK, XV, WQB, WKB, WVB, WOB);
  gemm_qkv<<<768, 256, 0, stream>>>(XQ, XK, XV, WQB, bq, bk, bv, gate, QB, KB, VTB);
  attn_kernel<<<dim3(64, 16, 2), 128, 0, stream>>>(QB, KB, VTB, OPp, LP);
  merge_kernel<<<2048, 256, 0, stream>>>(OPp, LP, AOB);
  gemm_out<<<512, 256, 0, stream>>>(AOB, WOB, bo, out);
}

// Round 7
// 240.125 us; speedup vs baseline: 1.0170x; 1.0170x over previous
//
#include <hip/hip_runtime.h>
#include <hip/hip_bf16.h>
#include <cstdint>

// GatedMultiheadAttention: B=2, N=2048, E=1024, H=16, D=64
// R7 (= R6 with compile fix): split-K attention with conflict-free LDS:
//  - pi-interleaved S tiles (S col l15 of tile j <-> key 2*l15+j) so each lane's
//    two P values are adjacent keys -> one packed ds_write_b32 (manual bf16x2
//    pack; __floats2bfloat162_rn doesn't exist in ROCm 7.2).
//  - K swizzle (r>>1)&7, V/P swizzle (r>>1)&3 (R5's (r>>2)&3 was 8-way in-phase).
// ws (48MB): weights 0-8 (LP overlays dead WQB), XQ 8-16 (->AOB),
// XK/XV 16-32 (->OPp), QB 32-40, KB 40-48. VTB = d_out (dead until final GEMM).

#define DEV __device__ __forceinline__
typedef __attribute__((ext_vector_type(8))) short bf16x8;
typedef __attribute__((ext_vector_type(4))) float f32x4;
typedef unsigned short u16;

DEV void async16(const void* g, void* l) {
  __builtin_amdgcn_global_load_lds(
      (const __attribute__((address_space(1))) unsigned int*)g,
      (__attribute__((address_space(3))) unsigned int*)l, 16, 0, 0);
}

DEV u16 bf16_rne(float f) {
  unsigned int u = __builtin_bit_cast(unsigned int, f);
  u += 0x7FFFu + ((u >> 16) & 1u);
  return (u16)(u >> 16);
}

DEV u16 cvt16(float x) {
  __hip_bfloat16 h = __float2bfloat16(x);
  return __builtin_bit_cast(u16, h);
}

DEV unsigned pack2(float lo, float hi) {
  return (unsigned)cvt16(lo) | ((unsigned)cvt16(hi) << 16);
}

// ---------------- one fused cast: q,k,v + 4 weights ----------------
__global__ __launch_bounds__(256) void cast_all(
    const float* __restrict__ q, const float* __restrict__ k, const float* __restrict__ v,
    const float* __restrict__ Wq, const float* __restrict__ Wk,
    const float* __restrict__ Wv, const float* __restrict__ Wo,
    u16* __restrict__ XQ, u16* __restrict__ XK, u16* __restrict__ XV,
    u16* __restrict__ WQB, u16* __restrict__ WKB, u16* __restrict__ WVB,
    u16* __restrict__ WOB) {
  int idx = blockIdx.x * 256 + threadIdx.x;  // one 8-elem item each
  const float* src; u16* dst; int i;
  if      (idx <  524288) { src = q;  dst = XQ;  i = idx; }
  else if (idx < 1048576) { src = k;  dst = XK;  i = idx -  524288; }
  else if (idx < 1572864) { src = v;  dst = XV;  i = idx - 1048576; }
  else if (idx < 1703936) { src = Wq; dst = WQB; i = idx - 1572864; }
  else if (idx < 1835008) { src = Wk; dst = WKB; i = idx - 1703936; }
  else if (idx < 1966080) { src = Wv; dst = WVB; i = idx - 1835008; }
  else                    { src = Wo; dst = WOB; i = idx - 1966080; }
  const float4* p = (const float4*)src + (size_t)i * 2;
  float4 a = p[0], b = p[1];
  union { u16 us[8]; uint4 vv; } u;
  u.us[0] = bf16_rne(a.x); u.us[1] = bf16_rne(a.y);
  u.us[2] = bf16_rne(a.z); u.us[3] = bf16_rne(a.w);
  u.us[4] = bf16_rne(b.x); u.us[5] = bf16_rne(b.y);
  u.us[6] = bf16_rne(b.z); u.us[7] = bf16_rne(b.w);
  ((uint4*)dst)[i] = u.vv;
}

// ---------------- fused QKV projection GEMM (768 blocks, 128x128, dbuf) ------
// seg = bx>>8: 0=Q (gate-scale folded), 1=K, 2=V (writes V^T into d_out).
__global__ __launch_bounds__(256, 3) void gemm_qkv(
    const u16* __restrict__ XQ, const u16* __restrict__ XK, const u16* __restrict__ XV,
    const u16* __restrict__ Wb,  // WQ|WK|WV contiguous, 1M elems apart
    const float* __restrict__ bq, const float* __restrict__ bkb, const float* __restrict__ bv,
    const float* __restrict__ gate,
    u16* __restrict__ QB, u16* __restrict__ KB, u16* __restrict__ VTB) {
  __shared__ __attribute__((aligned(16))) u16 As[2][128 * 32];
  __shared__ __attribute__((aligned(16))) u16 Bs[2][128 * 32];
  const int t = threadIdx.x, lane = t & 63, w = t >> 6;
  const int l15 = lane & 15, quad = lane >> 4;
  const int seg = blockIdx.x >> 8, inner = blockIdx.x & 255;
  const int bm = inner >> 3, bn = inner & 7;
  const int m0 = bm << 7, n0 = bn << 7;
  const u16* A = (seg == 0) ? XQ : (seg == 1) ? XK : XV;
  const u16* W = Wb + (long)seg * 1048576;
  const int wm = (w >> 1) << 6, wn = (w & 1) << 6;
  const int r0 = t >> 2, cc0 = (t & 3) * 8;
  const u16* gA0 = A + (long)(m0 + r0) * 1024 + cc0;
  const u16* gA1 = gA0 + 64 * 1024;
  const u16* gB0 = W + (long)(n0 + r0) * 1024 + cc0;
  const u16* gB1 = gB0 + 64 * 1024;

  async16(gA0, &As[0][t * 8]); async16(gA1, &As[0][(t + 256) * 8]);
  async16(gB0, &Bs[0][t * 8]); async16(gB1, &Bs[0][(t + 256) * 8]);

  f32x4 acc[4][4] = {};
  for (int k0 = 0; k0 < 1024; k0 += 32) {
    const int cur = (k0 >> 5) & 1;
    __syncthreads();
    if (k0 + 32 < 1024) {
      const int kn = k0 + 32, nb = cur ^ 1;
      async16(gA0 + kn, &As[nb][t * 8]); async16(gA1 + kn, &As[nb][(t + 256) * 8]);
      async16(gB0 + kn, &Bs[nb][t * 8]); async16(gB1 + kn, &Bs[nb][(t + 256) * 8]);
    }
    bf16x8 af[4], bfm[4];
#pragma unroll
    for (int i = 0; i < 4; i++)
      af[i] = *(const bf16x8*)&As[cur][(wm + i * 16 + l15) * 32 + quad * 8];
#pragma unroll
    for (int j = 0; j < 4; j++)
      bfm[j] = *(const bf16x8*)&Bs[cur][(wn + j * 16 + l15) * 32 + quad * 8];
#pragma unroll
    for (int i = 0; i < 4; i++)
#pragma unroll
      for (int j = 0; j < 4; j++)
        acc[i][j] = __builtin_amdgcn_mfma_f32_16x16x32_bf16(af[i], bfm[j], acc[i][j], 0, 0, 0);
  }

  if (seg == 2) {  // V: bias + transposed write V^T[(b*1024+col)*2048 + n]
#pragma unroll
    for (int i = 0; i < 4; i++) {
      int token = m0 + wm + i * 16 + quad * 4;
      int bb_ = token >> 11, n = token & 2047;
#pragma unroll
      for (int j = 0; j < 4; j++) {
        int col = n0 + wn + j * 16 + l15;
        float bb = bv[col];
        union { u16 us[4]; uint2 u2; } pk;
#pragma unroll
        for (int r = 0; r < 4; r++) pk.us[r] = bf16_rne(acc[i][j][r] + bb);
        *(uint2*)&VTB[(long)(bb_ * 1024 + col) * 2048 + n] = pk.u2;
      }
    }
  } else {
    const float* bias = seg ? bkb : bq;
    u16* C = seg ? KB : QB;
#pragma unroll
    for (int j = 0; j < 4; j++) {
      int col = n0 + wn + j * 16 + l15;
      float bb = bias[col];
      float scl = 1.f;
      if (seg == 0) {
        float g = gate[col >> 6];
        float sig = 1.f / (1.f + __builtin_amdgcn_exp2f(-g * 1.44269504f));
        scl = sig * 0.125f * 1.44269504f;
      }
#pragma unroll
      for (int i = 0; i < 4; i++) {
        int row = m0 + wm + i * 16 + quad * 4;
#pragma unroll
        for (int r = 0; r < 4; r++)
          C[(long)(row + r) * 1024 + col] = bf16_rne((acc[i][j][r] + bb) * scl);
      }
    }
  }
}

// ---------------- out-proj GEMM: 64x128 tiles, dbuf, fp32 out ----------------
__global__ __launch_bounds__(256, 2) void gemm_out(
    const u16* __restrict__ A, const u16* __restrict__ W,
    const float* __restrict__ bias, float* __restrict__ Cf) {
  __shared__ __attribute__((aligned(16))) u16 As[2][64 * 32];
  __shared__ __attribute__((aligned(16))) u16 Bs[2][128 * 32];
  const int t = threadIdx.x, lane = t & 63, w = t >> 6;
  const int l15 = lane & 15, quad = lane >> 4;
  const int bm = blockIdx.x >> 3, bn = blockIdx.x & 7;
  const int m0 = bm << 6, n0 = bn << 7;
  const int wm = (w >> 1) << 5, wn = (w & 1) << 6;
  const int r0 = t >> 2, cc0 = (t & 3) * 8;
  const u16* gA = A + (long)(m0 + r0) * 1024 + cc0;
  const u16* gB0 = W + (long)(n0 + r0) * 1024 + cc0;
  const u16* gB1 = gB0 + 64 * 1024;

  async16(gA, &As[0][t * 8]);
  async16(gB0, &Bs[0][t * 8]); async16(gB1, &Bs[0][(t + 256) * 8]);

  f32x4 acc[2][4] = {};
  for (int k0 = 0; k0 < 1024; k0 += 32) {
    const int cur = (k0 >> 5) & 1;
    __syncthreads();
    if (k0 + 32 < 1024) {
      const int kn = k0 + 32, nb = cur ^ 1;
      async16(gA + kn, &As[nb][t * 8]);
      async16(gB0 + kn, &Bs[nb][t * 8]); async16(gB1 + kn, &Bs[nb][(t + 256) * 8]);
    }
    bf16x8 af[2], bfm[4];
#pragma unroll
    for (int i = 0; i < 2; i++)
      af[i] = *(const bf16x8*)&As[cur][(wm + i * 16 + l15) * 32 + quad * 8];
#pragma unroll
    for (int j = 0; j < 4; j++)
      bfm[j] = *(const bf16x8*)&Bs[cur][(wn + j * 16 + l15) * 32 + quad * 8];
#pragma unroll
    for (int i = 0; i < 2; i++)
#pragma unroll
      for (int j = 0; j < 4; j++)
        acc[i][j] = __builtin_amdgcn_mfma_f32_16x16x32_bf16(af[i], bfm[j], acc[i][j], 0, 0, 0);
  }

#pragma unroll
  for (int j = 0; j < 4; j++) {
    int col = n0 + wn + j * 16 + l15;
    float bb = bias[col];
#pragma unroll
    for (int i = 0; i < 2; i++) {
      int row = m0 + wm + i * 16 + quad * 4;
#pragma unroll
      for (int r = 0; r < 4; r++)
        Cf[(long)(row + r) * 1024 + col] = acc[i][j][r] + bb;
    }
  }
}

// ---------------- split-K flash attention (conflict-free LDS) ----------------
// grid (64,16,2) x 128 thr: bx = qt*2 + ksplit; 2 waves x 32 q-rows, BK=32.
// pi-interleave: S-tile j col l15 <-> global key 2*l15+j (K B-frag rows 2*l15+j,
// swizzle (r>>1)&7 == l15&7). P: lane packs keys (2*l15, 2*l15+1) -> one b32.
// Vs/Ps 64B rows with (r>>1)&3 chunk swizzle. LDS 20KB -> 8 blocks/CU.
__global__ __launch_bounds__(128, 4) void attn_kernel(
    const u16* __restrict__ Q, const u16* __restrict__ Kb,
    const u16* __restrict__ Vt, u16* __restrict__ Op, float* __restrict__ lp) {
  __shared__ __attribute__((aligned(16))) u16 Ks[2][32 * 64];  // [key][d], 128B rows
  __shared__ __attribute__((aligned(16))) u16 Vs[2][64 * 32];  // [d][key], 64B rows
  __shared__ __attribute__((aligned(16))) u16 Ps[2][32 * 32];  // per-wave [q][key], 64B rows
  const int t = threadIdx.x, lane = t & 63, w = t >> 6;
  const int l15 = lane & 15, quad = lane >> 4;
  const int qt = blockIdx.x >> 1, ksp = blockIdx.x & 1;
  const int h = blockIdx.y, b = blockIdx.z;
  const int q0 = qt * 64, tok0 = b * 2048, key0 = ksp * 1024;
  const u16* Kbase = Kb + (long)tok0 * 1024 + h * 64;
  const u16* Vbase = Vt + (long)(b * 1024 + h * 64) * 2048;

  // loop-invariant Q fragments (wave rows q0 + w*32 .. +31)
  bf16x8 aq[2][2];
#pragma unroll
  for (int i = 0; i < 2; i++) {
    long row = tok0 + q0 + w * 32 + i * 16 + l15;
#pragma unroll
    for (int ks = 0; ks < 2; ks++)
      aq[i][ks] = *(const bf16x8*)&Q[row * 1024 + h * 64 + ks * 32 + quad * 8];
  }

  // stage kt=0. K: chunk ^ ((row>>1)&7); V: chunk ^ ((row>>1)&3). Swizzle on
  // the GLOBAL chunk so global_load_lds lane-contiguity holds.
#pragma unroll
  for (int i = 0; i < 2; i++) {
    int c = i * 128 + t;
    int rk = c >> 3, ck = c & 7, cks = ck ^ ((rk >> 1) & 7);
    async16(&Kbase[(long)(key0 + rk) * 1024 + cks * 8], &Ks[0][c * 8]);
    int rv = c >> 2, cv = c & 3, cvs = cv ^ ((rv >> 1) & 3);
    async16(&Vbase[(long)rv * 2048 + key0 + cvs * 8], &Vs[0][c * 8]);
  }

  float l_st[2][4] = {};
  f32x4 O[2][4] = {};

  for (int kt = 0; kt < 32; kt++) {
    const int cur = kt & 1;
    __syncthreads();
    if (kt + 1 < 32) {
      const int k0n = key0 + (kt + 1) * 32, nb = cur ^ 1;
#pragma unroll
      for (int i = 0; i < 2; i++) {
        int c = i * 128 + t;
        int rk = c >> 3, ck = c & 7, cks = ck ^ ((rk >> 1) & 7);
        async16(&Kbase[(long)(k0n + rk) * 1024 + cks * 8], &Ks[nb][c * 8]);
        int rv = c >> 2, cv = c & 3, cvs = cv ^ ((rv >> 1) & 3);
        async16(&Vbase[(long)rv * 2048 + k0n + cvs * 8], &Vs[nb][c * 8]);
      }
    }

    // S = Q K^T (exp2 domain), pi-interleaved: tile j col l15 = key 2*l15+j
    f32x4 s[2][2] = {};
#pragma unroll
    for (int ks = 0; ks < 2; ks++) {
      bf16x8 bk_[2];
#pragma unroll
      for (int j = 0; j < 2; j++) {
        int rl = 2 * l15 + j;
        bk_[j] = *(const bf16x8*)&Ks[cur][rl * 64 + (((ks * 4 + quad) ^ (l15 & 7))) * 8];
      }
#pragma unroll
      for (int i = 0; i < 2; i++)
#pragma unroll
        for (int j = 0; j < 2; j++)
          s[i][j] = __builtin_amdgcn_mfma_f32_16x16x32_bf16(aq[i][ks], bk_[j], s[i][j], 0, 0, 0);
    }

    // exp2 + deferred l + packed P write (keys 2*l15, 2*l15+1 adjacent)
#pragma unroll
    for (int i = 0; i < 2; i++) {
#pragma unroll
      for (int r = 0; r < 4; r++) {
        float p0 = __builtin_amdgcn_exp2f(s[i][0][r]);
        float p1 = __builtin_amdgcn_exp2f(s[i][1][r]);
        l_st[i][r] += p0 + p1;
        const int prow = i * 16 + quad * 4 + r;
        const int chs = (l15 >> 2) ^ ((prow >> 1) & 3);
        *(unsigned*)&Ps[w][prow * 32 + chs * 8 + (l15 & 3) * 2] = pack2(p0, p1);
      }
    }

    // O += P @ V (single K=32 MFMA pass)
    {
      bf16x8 ap[2], bv_[4];
#pragma unroll
      for (int i = 0; i < 2; i++) {
        int rl = i * 16 + l15;
        ap[i] = *(const bf16x8*)&Ps[w][rl * 32 + ((quad ^ ((rl >> 1) & 3))) * 8];
      }
#pragma unroll
      for (int dj = 0; dj < 4; dj++) {
        int rl = dj * 16 + l15;
        bv_[dj] = *(const bf16x8*)&Vs[cur][rl * 32 + ((quad ^ ((rl >> 1) & 3))) * 8];
      }
#pragma unroll
      for (int i = 0; i < 2; i++)
#pragma unroll
        for (int dj = 0; dj < 4; dj++)
          O[i][dj] = __builtin_amdgcn_mfma_f32_16x16x32_bf16(ap[i], bv_[dj], O[i][dj], 0, 0, 0);
    }
  }

  // epilogue: per-row l reduced over 16 lanes; store raw O (bf16) + l (f32)
#pragma unroll
  for (int i = 0; i < 2; i++) {
#pragma unroll
    for (int r = 0; r < 4; r++) {
      float ls = l_st[i][r];
      ls += __shfl_xor(ls, 1); ls += __shfl_xor(ls, 2);
      ls += __shfl_xor(ls, 4); ls += __shfl_xor(ls, 8);
      long row = tok0 + q0 + w * 32 + i * 16 + quad * 4 + r;
#pragma unroll
      for (int dj = 0; dj < 4; dj++)
        Op[(long)ksp * 4194304 + row * 1024 + h * 64 + dj * 16 + l15] = cvt16(O[i][dj][r]);
      if (l15 == 0) lp[ksp * 65536 + (int)row * 16 + h] = ls;
    }
  }
}

// ---------------- merge split-K partials: AO = (O0+O1)/(l0+l1) ----------------
__global__ __launch_bounds__(256) void merge_kernel(
    const u16* __restrict__ Op, const float* __restrict__ lp,
    u16* __restrict__ AO) {
  int idx = blockIdx.x * 256 + threadIdx.x;  // 524288 chunks of 8 elems
  int tok = idx >> 7, rem = idx & 127, h = rem >> 3;
  float inv = 1.f / (lp[tok * 16 + h] + lp[65536 + tok * 16 + h]);
  union { uint4 v; u16 us[8]; } ua, ub, uo;
  ua.v = ((const uint4*)Op)[idx];
  ub.v = ((const uint4*)Op)[idx + 524288];
#pragma unroll
  for (int j = 0; j < 8; j++) {
    float fa = __builtin_bit_cast(float, (unsigned)((unsigned)ua.us[j] << 16));
    float fb = __builtin_bit_cast(float, (unsigned)((unsigned)ub.us[j] << 16));
    uo.us[j] = cvt16((fa + fb) * inv);
  }
  ((uint4*)AO)[idx] = uo.v;
}

extern "C" void kernel_launch(void* const* d_in, const int* in_sizes, int n_in,
                              void* d_out, int out_size, void* d_ws, size_t ws_size,
                              hipStream_t stream) {
  const float* q  = (const float*)d_in[0];
  const float* k  = (const float*)d_in[1];
  const float* v  = (const float*)d_in[2];
  const float* Wq = (const float*)d_in[3];
  const float* bq = (const float*)d_in[4];
  const float* Wk = (const float*)d_in[5];
  const float* bk = (const float*)d_in[6];
  const float* Wv = (const float*)d_in[7];
  const float* bv = (const float*)d_in[8];
  const float* Wo = (const float*)d_in[9];
  const float* bo = (const float*)d_in[10];
  const float* gate = (const float*)d_in[11];
  float* out = (float*)d_out;
  char* ws = (char*)d_ws;

  const size_t MB = 1u << 20;
  u16* WQB = (u16*)(ws + 0 * MB);   // WQ|WK|WV|WO contiguous (2MB each)
  u16* WKB = (u16*)(ws + 2 * MB);
  u16* WVB = (u16*)(ws + 4 * MB);
  u16* WOB = (u16*)(ws + 6 * MB);
  u16* XQ  = (u16*)(ws + 8 * MB);
  u16* XK  = (u16*)(ws + 16 * MB);
  u16* XV  = (u16*)(ws + 24 * MB);
  u16* QB  = (u16*)(ws + 32 * MB);
  u16* KB  = (u16*)(ws + 40 * MB);
  u16* AOB = (u16*)(ws + 8 * MB);     // over dead XQ
  u16* OPp = (u16*)(ws + 16 * MB);    // 16MB partial O (over dead XK/XV)
  float* LP = (float*)(ws + 0 * MB);  // 512KB partial l (over dead WQB)
  u16* VTB = (u16*)d_out;             // d_out as scratch until final GEMM

  cast_all<<<8192, 256, 0, stream>>>(q, k, v, Wq, Wk, Wv, Wo,
                                     XQ, XK, XV, WQB, WKB, WVB, WOB);
  gemm_qkv<<<768, 256, 0, stream>>>(XQ, XK, XV, WQB, bq, bk, bv, gate, QB, KB, VTB);
  attn_kernel<<<dim3(64, 16, 2), 128, 0, stream>>>(QB, KB, VTB, OPp, LP);
  merge_kernel<<<2048, 256, 0, stream>>>(OPp, LP, AOB);
  gemm_out<<<512, 256, 0, stream>>>(AOB, WOB, bo, out);
}